// Round 5
// baseline (156.095 us; speedup 1.0000x reference)
//
#include <hip/hip_runtime.h>

#define BB 8
#define NN 2048
#define IND 128
#define OUTD 64
#define ALPHA 0.2f

typedef __attribute__((ext_vector_type(8))) short bf16x8;
typedef __attribute__((ext_vector_type(4))) float f32x4;
typedef unsigned int u32;

// ---------------- K1: h = x@W -> h_T (bf16 hi/lo, [B][64][2048]), si, sj ----
__global__ __launch_bounds__(256) void k1_hproj(const float* __restrict__ x,
                                                const float* __restrict__ W,
                                                const float* __restrict__ a,
                                                short* __restrict__ hT_hi,
                                                short* __restrict__ hT_lo,
                                                float* __restrict__ si,
                                                float* __restrict__ sj) {
    __shared__ float Wl[IND * OUTD];     // 32 KB
    __shared__ float xl[16][IND];        // 8 KB
    __shared__ float tile[16][OUTD + 1]; // h tile for transpose (pad 65)
    int t = threadIdx.x, lane = t & 63, wave = t >> 6;

    const float4* W4 = (const float4*)W;
    float4* Wl4 = (float4*)Wl;
    #pragma unroll
    for (int q = 0; q < 8; ++q) Wl4[t + q * 256] = W4[t + q * 256];

    int row0 = blockIdx.x * 16;                    // global row in [0, B*N)
    const float4* x4 = (const float4*)(x + (size_t)row0 * IND);
    float4* xl4 = (float4*)&xl[0][0];
    xl4[t] = x4[t];
    xl4[t + 256] = x4[t + 256];
    __syncthreads();

    float a1v = a[lane];
    float a2v = a[OUTD + lane];

    float acc[4] = {0.f, 0.f, 0.f, 0.f};
    int rbase = wave * 4;
    for (int k = 0; k < IND; k += 4) {
        float4 xv0 = *(const float4*)&xl[rbase + 0][k];
        float4 xv1 = *(const float4*)&xl[rbase + 1][k];
        float4 xv2 = *(const float4*)&xl[rbase + 2][k];
        float4 xv3 = *(const float4*)&xl[rbase + 3][k];
        #pragma unroll
        for (int q = 0; q < 4; ++q) {
            float w = Wl[(k + q) * OUTD + lane];
            acc[0] = fmaf(((const float*)&xv0)[q], w, acc[0]);
            acc[1] = fmaf(((const float*)&xv1)[q], w, acc[1]);
            acc[2] = fmaf(((const float*)&xv2)[q], w, acc[2]);
            acc[3] = fmaf(((const float*)&xv3)[q], w, acc[3]);
        }
    }
    #pragma unroll
    for (int rr = 0; rr < 4; ++rr) {
        size_t grow = (size_t)row0 + rbase + rr;
        tile[rbase + rr][lane] = acc[rr];
        float v1 = acc[rr] * a1v;
        float v2 = acc[rr] * a2v;
        #pragma unroll
        for (int o = 32; o; o >>= 1) {
            v1 += __shfl_xor(v1, o);
            v2 += __shfl_xor(v2, o);
        }
        if (lane == 0) { si[grow] = v1; sj[grow] = v2; }
    }
    __syncthreads();

    // transpose + bf16 hi/lo split: thread t -> d = t>>2, k-quad = (t&3)*4
    int d = t >> 2, kq = (t & 3) * 4;
    int b = row0 >> 11;                // batch
    int krow = (row0 & (NN - 1)) + kq; // k index within batch
    float v0 = tile[kq + 0][d], v1 = tile[kq + 1][d];
    float v2 = tile[kq + 2][d], v3 = tile[kq + 3][d];
    u32 b0 = __float_as_uint(v0), b1 = __float_as_uint(v1);
    u32 b2 = __float_as_uint(v2), b3 = __float_as_uint(v3);
    u32 h0 = b0 & 0xffff0000u, h1 = b1 & 0xffff0000u;
    u32 h2 = b2 & 0xffff0000u, h3 = b3 & 0xffff0000u;
    float l0 = v0 - __uint_as_float(h0), l1 = v1 - __uint_as_float(h1);
    float l2 = v2 - __uint_as_float(h2), l3 = v3 - __uint_as_float(h3);
    uint2 hi2, lo2;
    hi2.x = (b0 >> 16) | h1;
    hi2.y = (b2 >> 16) | h3;
    lo2.x = (__float_as_uint(l0) >> 16) | (__float_as_uint(l1) & 0xffff0000u);
    lo2.y = (__float_as_uint(l2) >> 16) | (__float_as_uint(l3) & 0xffff0000u);
    size_t off = ((size_t)b * OUTD + d) * NN + krow;   // in shorts (8B aligned)
    *(uint2*)(hT_hi + off) = hi2;
    *(uint2*)(hT_lo + off) = lo2;
}

// ---------------- K2: adj -> byte bitmask + invS. Fully coalesced. ----------
// One wave per row. lane handles j = q*256 + lane*4 .. +4 per pass q.
__global__ __launch_bounds__(256) void k2_mask(const int* __restrict__ adj,
                                               const float* __restrict__ si,
                                               const float* __restrict__ sj,
                                               float* __restrict__ invS,
                                               unsigned char* __restrict__ mask) {
    int t = threadIdx.x, lane = t & 63, w = t >> 6;
    int row = blockIdx.x * 4 + w;      // 4096 blocks x 4 waves = 16384 rows
    int b = row >> 11;
    float s_i = si[row];
    const int4* arow = (const int4*)(adj + (size_t)row * NN);
    const float* sjb = sj + (size_t)b * NN;

    float sum = 0.f;
    #pragma unroll
    for (int q = 0; q < 8; ++q) {
        int4 av = arow[q * 64 + lane];
        float4 sv = *(const float4*)(sjb + q * 256 + lane * 4);
        unsigned nib = 0;
        float e, pe;
        e = s_i + sv.x; e = e > 0.f ? e : ALPHA * e; pe = __expf(e);
        if (av.x > 0) { nib |= 1u; sum += pe; }
        e = s_i + sv.y; e = e > 0.f ? e : ALPHA * e; pe = __expf(e);
        if (av.y > 0) { nib |= 2u; sum += pe; }
        e = s_i + sv.z; e = e > 0.f ? e : ALPHA * e; pe = __expf(e);
        if (av.z > 0) { nib |= 4u; sum += pe; }
        e = s_i + sv.w; e = e > 0.f ? e : ALPHA * e; pe = __expf(e);
        if (av.w > 0) { nib |= 8u; sum += pe; }
        // byte covers j [8k,8k+8): even lane -> bits 0..3, odd lane -> bits 4..7
        unsigned pn = (unsigned)__shfl_xor((int)nib, 1);
        if (!(lane & 1))
            mask[(size_t)row * 256 + q * 32 + (lane >> 1)] = (unsigned char)(nib | (pn << 4));
    }
    #pragma unroll
    for (int o = 32; o; o >>= 1) sum += __shfl_xor(sum, o);
    if (lane == 0) invS[row] = sum > 0.f ? 1.0f / sum : 0.f;
}

// ---------------- K3: phase A coalesced attn write; phase B MFMA PV --------
__global__ __launch_bounds__(256) void k3_attn_pv(const unsigned char* __restrict__ mask,
                                                  const float* __restrict__ si,
                                                  const float* __restrict__ sj,
                                                  const float* __restrict__ invS,
                                                  const short* __restrict__ hT_hi,
                                                  const short* __restrict__ hT_lo,
                                                  float* __restrict__ attn,
                                                  float* __restrict__ hp) {
    __shared__ float si_s[16], inv_s[16];
    __shared__ f32x4 red[4][4][64];              // [wave][n-tile][lane] 16 KB

    int t = threadIdx.x, lane = t & 63, w = t >> 6;
    int bk = blockIdx.x;
    int b = bk >> 7;                 // 128 blocks per batch
    int i0 = (bk & 127) * 16;
    size_t rowbase = (size_t)b * NN + i0;
    const float* sjb = sj + (size_t)b * NN;

    if (t < 16) {
        si_s[t] = si[rowbase + t];
        inv_s[t] = invS[rowbase + t];
    }
    __syncthreads();

    // ---- phase A: linear streaming attention write (coalesced) ----
    #pragma unroll 4
    for (int it = 0; it < 32; ++it) {
        int idx = it * 256 + t;            // 0 .. 8191
        int row = idx >> 9;                // 16 rows x 512 float4 each
        int col = (idx & 511) << 2;
        float4 sv = *(const float4*)(sjb + col);
        unsigned char mb = mask[(rowbase + row) * 256 + (col >> 3)];
        unsigned nib = (mb >> (col & 4)) & 0xFu;
        float s_i = si_s[row], inv = inv_s[row];
        float4 pv;
        float e;
        e = s_i + sv.x; e = e > 0.f ? e : ALPHA * e;
        pv.x = (nib & 1u) ? __expf(e) * inv : 0.f;
        e = s_i + sv.y; e = e > 0.f ? e : ALPHA * e;
        pv.y = (nib & 2u) ? __expf(e) * inv : 0.f;
        e = s_i + sv.z; e = e > 0.f ? e : ALPHA * e;
        pv.z = (nib & 4u) ? __expf(e) * inv : 0.f;
        e = s_i + sv.w; e = e > 0.f ? e : ALPHA * e;
        pv.w = (nib & 8u) ? __expf(e) * inv : 0.f;
        *(float4*)(attn + (rowbase + row) * (size_t)NN + col) = pv;
    }

    // ---- phase B: MFMA PV over wave-disjoint K-range of 512 ----
    int m = lane & 15, g = lane >> 4;
    float si_m = si_s[m];
    float inv_m = inv_s[m];
    const short* bh_base = hT_hi + ((size_t)b * OUTD + m) * NN;
    const short* bl_base = hT_lo + ((size_t)b * OUTD + m) * NN;

    f32x4 acc[4];
    #pragma unroll
    for (int tt = 0; tt < 4; ++tt) acc[tt] = (f32x4){0.f, 0.f, 0.f, 0.f};

    for (int step = 0; step < 16; ++step) {
        int jb = w * 512 + step * 32 + g * 8;
        float4 s0 = *(const float4*)(sjb + jb);
        float4 s1 = *(const float4*)(sjb + jb + 4);
        unsigned mb = mask[(rowbase + m) * 256 + (jb >> 3)];
        float sv[8] = {s0.x, s0.y, s0.z, s0.w, s1.x, s1.y, s1.z, s1.w};
        float p[8];
        #pragma unroll
        for (int q = 0; q < 8; ++q) {
            float e = si_m + sv[q];
            e = e > 0.f ? e : ALPHA * e;
            float pe = __expf(e) * inv_m;
            p[q] = ((mb >> q) & 1u) ? pe : 0.f;
        }

        // split p into bf16 hi/lo (truncation; lo = p - hi is exact)
        union { bf16x8 v; u32 u[4]; } ph, pl;
        #pragma unroll
        for (int q = 0; q < 4; ++q) {
            u32 c0 = __float_as_uint(p[2 * q]), c1 = __float_as_uint(p[2 * q + 1]);
            u32 t0 = c0 & 0xffff0000u, t1 = c1 & 0xffff0000u;
            float d0 = p[2 * q] - __uint_as_float(t0);
            float d1 = p[2 * q + 1] - __uint_as_float(t1);
            ph.u[q] = (c0 >> 16) | t1;
            pl.u[q] = (__float_as_uint(d0) >> 16) | (__float_as_uint(d1) & 0xffff0000u);
        }

        #pragma unroll
        for (int tt = 0; tt < 4; ++tt) {
            bf16x8 bh = *(const bf16x8*)(bh_base + (size_t)tt * 16 * NN + jb);
            bf16x8 bl = *(const bf16x8*)(bl_base + (size_t)tt * 16 * NN + jb);
            acc[tt] = __builtin_amdgcn_mfma_f32_16x16x32_bf16(ph.v, bh, acc[tt], 0, 0, 0);
            acc[tt] = __builtin_amdgcn_mfma_f32_16x16x32_bf16(ph.v, bl, acc[tt], 0, 0, 0);
            acc[tt] = __builtin_amdgcn_mfma_f32_16x16x32_bf16(pl.v, bh, acc[tt], 0, 0, 0);
        }
    }

    // ---- cross-wave reduce of D (16 rows x 64 dims) ----
    #pragma unroll
    for (int tt = 0; tt < 4; ++tt) red[w][tt][lane] = acc[tt];
    __syncthreads();

    for (int idx = t; idx < 16 * OUTD; idx += 256) {
        int row = idx >> 6, n = idx & 63;
        int ln = (row >> 2) * 16 + (n & 15);
        int reg = row & 3;
        float v = ((const float*)&red[0][n >> 4][ln])[reg]
                + ((const float*)&red[1][n >> 4][ln])[reg]
                + ((const float*)&red[2][n >> 4][ln])[reg]
                + ((const float*)&red[3][n >> 4][ln])[reg];
        hp[(rowbase + row) * OUTD + n] = v;
    }
}

extern "C" void kernel_launch(void* const* d_in, const int* in_sizes, int n_in,
                              void* d_out, int out_size, void* d_ws, size_t ws_size,
                              hipStream_t stream) {
    const float* x   = (const float*)d_in[0];
    const int*   adj = (const int*)d_in[1];
    const float* W   = (const float*)d_in[2];
    const float* a   = (const float*)d_in[3];

    float* out  = (float*)d_out;
    float* hp   = out;                                  // (B,N,OUT)
    float* attn = out + (size_t)BB * NN * OUTD;         // (B,N,N)

    char* ws = (char*)d_ws;
    short* hT_hi = (short*)ws;                           // 2 MB
    short* hT_lo = hT_hi + (size_t)BB * OUTD * NN;       // 2 MB
    float* si    = (float*)(hT_lo + (size_t)BB * OUTD * NN);
    float* sj    = si + (size_t)BB * NN;
    float* invS  = sj + (size_t)BB * NN;
    unsigned char* mask = (unsigned char*)(invS + (size_t)BB * NN);  // 4 MB

    k1_hproj<<<BB * NN / 16, 256, 0, stream>>>(x, W, a, hT_hi, hT_lo, si, sj);
    k2_mask<<<BB * NN / 4, 256, 0, stream>>>(adj, si, sj, invS, mask);
    k3_attn_pv<<<BB * NN / 16, 256, 0, stream>>>(mask, si, sj, invS, hT_hi, hT_lo, attn, hp);
}

// Round 7
// 124.936 us; speedup vs baseline: 1.2494x; 1.2494x over previous
//
#include <hip/hip_runtime.h>

#define BB 8
#define NN 2048
#define IND 128
#define OUTD 64
#define ALPHA 0.2f

typedef __attribute__((ext_vector_type(8))) short bf16x8;
typedef __attribute__((ext_vector_type(4))) float f32x4;
typedef unsigned int u32;

// ---------------- K1: h = x@W -> h_T (bf16 hi/lo, [B][64][2048]), si, sj ----
__global__ __launch_bounds__(256) void k1_hproj(const float* __restrict__ x,
                                                const float* __restrict__ W,
                                                const float* __restrict__ a,
                                                short* __restrict__ hT_hi,
                                                short* __restrict__ hT_lo,
                                                float* __restrict__ si,
                                                float* __restrict__ sj) {
    __shared__ float Wl[IND * OUTD];     // 32 KB
    __shared__ float xl[16][IND];        // 8 KB
    __shared__ float tile[16][OUTD + 1]; // h tile for transpose (pad 65)
    int t = threadIdx.x, lane = t & 63, wave = t >> 6;

    const float4* W4 = (const float4*)W;
    float4* Wl4 = (float4*)Wl;
    #pragma unroll
    for (int q = 0; q < 8; ++q) Wl4[t + q * 256] = W4[t + q * 256];

    int row0 = blockIdx.x * 16;                    // global row in [0, B*N)
    const float4* x4 = (const float4*)(x + (size_t)row0 * IND);
    float4* xl4 = (float4*)&xl[0][0];
    xl4[t] = x4[t];
    xl4[t + 256] = x4[t + 256];
    __syncthreads();

    float a1v = a[lane];
    float a2v = a[OUTD + lane];

    float acc[4] = {0.f, 0.f, 0.f, 0.f};
    int rbase = wave * 4;
    for (int k = 0; k < IND; k += 4) {
        float4 xv0 = *(const float4*)&xl[rbase + 0][k];
        float4 xv1 = *(const float4*)&xl[rbase + 1][k];
        float4 xv2 = *(const float4*)&xl[rbase + 2][k];
        float4 xv3 = *(const float4*)&xl[rbase + 3][k];
        #pragma unroll
        for (int q = 0; q < 4; ++q) {
            float w = Wl[(k + q) * OUTD + lane];
            acc[0] = fmaf(((const float*)&xv0)[q], w, acc[0]);
            acc[1] = fmaf(((const float*)&xv1)[q], w, acc[1]);
            acc[2] = fmaf(((const float*)&xv2)[q], w, acc[2]);
            acc[3] = fmaf(((const float*)&xv3)[q], w, acc[3]);
        }
    }
    #pragma unroll
    for (int rr = 0; rr < 4; ++rr) {
        size_t grow = (size_t)row0 + rbase + rr;
        tile[rbase + rr][lane] = acc[rr];
        float v1 = acc[rr] * a1v;
        float v2 = acc[rr] * a2v;
        #pragma unroll
        for (int o = 32; o; o >>= 1) {
            v1 += __shfl_xor(v1, o);
            v2 += __shfl_xor(v2, o);
        }
        if (lane == 0) { si[grow] = v1; sj[grow] = v2; }
    }
    __syncthreads();

    // transpose + bf16 hi/lo split: thread t -> d = t>>2, k-quad = (t&3)*4
    int d = t >> 2, kq = (t & 3) * 4;
    int b = row0 >> 11;                // batch
    int krow = (row0 & (NN - 1)) + kq; // k index within batch
    float v0 = tile[kq + 0][d], v1 = tile[kq + 1][d];
    float v2 = tile[kq + 2][d], v3 = tile[kq + 3][d];
    u32 b0 = __float_as_uint(v0), b1 = __float_as_uint(v1);
    u32 b2 = __float_as_uint(v2), b3 = __float_as_uint(v3);
    u32 h0 = b0 & 0xffff0000u, h1 = b1 & 0xffff0000u;
    u32 h2 = b2 & 0xffff0000u, h3 = b3 & 0xffff0000u;
    float l0 = v0 - __uint_as_float(h0), l1 = v1 - __uint_as_float(h1);
    float l2 = v2 - __uint_as_float(h2), l3 = v3 - __uint_as_float(h3);
    uint2 hi2, lo2;
    hi2.x = (b0 >> 16) | h1;
    hi2.y = (b2 >> 16) | h3;
    lo2.x = (__float_as_uint(l0) >> 16) | (__float_as_uint(l1) & 0xffff0000u);
    lo2.y = (__float_as_uint(l2) >> 16) | (__float_as_uint(l3) & 0xffff0000u);
    size_t off = ((size_t)b * OUTD + d) * NN + krow;   // in shorts (8B aligned)
    *(uint2*)(hT_hi + off) = hi2;
    *(uint2*)(hT_lo + off) = lo2;
}

// ---------------- K23: fused. 512 thr, 16 rows/block. ----------------------
// phase 1: adj -> LDS bitmask + invS (coalesced, high MLP)
// phase 2: streaming nontemporal attn write (coalesced, one row per iter)
// phase 3: MFMA PV (wave-disjoint K-ranges), cross-wave LDS reduce
__global__ __launch_bounds__(512) void k23(const int* __restrict__ adj,
                                           const float* __restrict__ si,
                                           const float* __restrict__ sj,
                                           const short* __restrict__ hT_hi,
                                           const short* __restrict__ hT_lo,
                                           float* __restrict__ attn,
                                           float* __restrict__ hp) {
    __shared__ unsigned char mask_lds[16][264];  // 4.2 KB
    __shared__ float si_lds[16], inv_lds[16];
    __shared__ f32x4 red[8][4][64];              // 32 KB

    int t = threadIdx.x, lane = t & 63, w = t >> 6;   // 8 waves
    int bk = blockIdx.x;
    int b = bk >> 7;                 // 128 blocks per batch
    int i0 = (bk & 127) * 16;
    size_t rowbase = (size_t)b * NN + i0;
    const float* sjb = sj + (size_t)b * NN;
    const f32x4* sjb4 = (const f32x4*)sjb;

    // ---- phase 1: wave w owns rows w*2, w*2+1 ----
    #pragma unroll
    for (int rr = 0; rr < 2; ++rr) {
        int row = w * 2 + rr;
        size_t grow = rowbase + row;
        float s_i = si[grow];
        const int4* arow = (const int4*)(adj + grow * NN);
        float sum = 0.f;
        #pragma unroll
        for (int q = 0; q < 8; ++q) {
            int4 av = arow[q * 64 + lane];
            f32x4 sv = sjb4[q * 64 + lane];
            unsigned nib = 0;
            float e, pe;
            e = s_i + sv.x; e = e > 0.f ? e : ALPHA * e; pe = __expf(e);
            if (av.x > 0) { nib |= 1u; sum += pe; }
            e = s_i + sv.y; e = e > 0.f ? e : ALPHA * e; pe = __expf(e);
            if (av.y > 0) { nib |= 2u; sum += pe; }
            e = s_i + sv.z; e = e > 0.f ? e : ALPHA * e; pe = __expf(e);
            if (av.z > 0) { nib |= 4u; sum += pe; }
            e = s_i + sv.w; e = e > 0.f ? e : ALPHA * e; pe = __expf(e);
            if (av.w > 0) { nib |= 8u; sum += pe; }
            unsigned pn = (unsigned)__shfl_xor((int)nib, 1);
            if (!(lane & 1))
                mask_lds[row][q * 32 + (lane >> 1)] = (unsigned char)(nib | (pn << 4));
        }
        #pragma unroll
        for (int o = 32; o; o >>= 1) sum += __shfl_xor(sum, o);
        if (lane == 0) {
            si_lds[row] = s_i;
            inv_lds[row] = sum > 0.f ? 1.0f / sum : 0.f;
        }
    }
    __syncthreads();

    // ---- phase 2: streaming attn write; iteration 'row' writes one full row
    {
        f32x4 sv = sjb4[t];                       // col = 4t, hoisted
        int mbyte = t >> 1;
        int nshift = (t & 1) * 4;
        #pragma unroll 4
        for (int row = 0; row < 16; ++row) {
            unsigned nib = ((unsigned)mask_lds[row][mbyte] >> nshift) & 0xFu;
            float s_i = si_lds[row], inv = inv_lds[row];
            f32x4 pv;
            float e;
            e = s_i + sv.x; e = e > 0.f ? e : ALPHA * e;
            pv.x = (nib & 1u) ? __expf(e) * inv : 0.f;
            e = s_i + sv.y; e = e > 0.f ? e : ALPHA * e;
            pv.y = (nib & 2u) ? __expf(e) * inv : 0.f;
            e = s_i + sv.z; e = e > 0.f ? e : ALPHA * e;
            pv.z = (nib & 4u) ? __expf(e) * inv : 0.f;
            e = s_i + sv.w; e = e > 0.f ? e : ALPHA * e;
            pv.w = (nib & 8u) ? __expf(e) * inv : 0.f;
            __builtin_nontemporal_store(pv,
                (f32x4*)(attn + (rowbase + row) * (size_t)NN + (size_t)t * 4));
        }
    }

    // ---- phase 3: MFMA PV over wave-disjoint K-range of 256 ----
    int m = lane & 15, g = lane >> 4;
    float si_m = si_lds[m];
    float inv_m = inv_lds[m];
    const short* bh_base = hT_hi + ((size_t)b * OUTD + m) * NN;
    const short* bl_base = hT_lo + ((size_t)b * OUTD + m) * NN;

    f32x4 acc[4];
    #pragma unroll
    for (int tt = 0; tt < 4; ++tt) acc[tt] = (f32x4){0.f, 0.f, 0.f, 0.f};

    for (int step = 0; step < 8; ++step) {
        int jb = w * 256 + step * 32 + g * 8;
        f32x4 s0 = *(const f32x4*)(sjb + jb);
        f32x4 s1 = *(const f32x4*)(sjb + jb + 4);
        unsigned mb = mask_lds[m][jb >> 3];
        float sv[8] = {s0.x, s0.y, s0.z, s0.w, s1.x, s1.y, s1.z, s1.w};
        float p[8];
        #pragma unroll
        for (int q = 0; q < 8; ++q) {
            float e = si_m + sv[q];
            e = e > 0.f ? e : ALPHA * e;
            float pe = __expf(e) * inv_m;
            p[q] = ((mb >> q) & 1u) ? pe : 0.f;
        }

        // split p into bf16 hi/lo (truncation; lo = p - hi is exact)
        union { bf16x8 v; u32 u[4]; } ph, pl;
        #pragma unroll
        for (int q = 0; q < 4; ++q) {
            u32 c0 = __float_as_uint(p[2 * q]), c1 = __float_as_uint(p[2 * q + 1]);
            u32 t0 = c0 & 0xffff0000u, t1 = c1 & 0xffff0000u;
            float d0 = p[2 * q] - __uint_as_float(t0);
            float d1 = p[2 * q + 1] - __uint_as_float(t1);
            ph.u[q] = (c0 >> 16) | t1;
            pl.u[q] = (__float_as_uint(d0) >> 16) | (__float_as_uint(d1) & 0xffff0000u);
        }

        #pragma unroll
        for (int tt = 0; tt < 4; ++tt) {
            bf16x8 bh = *(const bf16x8*)(bh_base + (size_t)tt * 16 * NN + jb);
            bf16x8 bl = *(const bf16x8*)(bl_base + (size_t)tt * 16 * NN + jb);
            acc[tt] = __builtin_amdgcn_mfma_f32_16x16x32_bf16(ph.v, bh, acc[tt], 0, 0, 0);
            acc[tt] = __builtin_amdgcn_mfma_f32_16x16x32_bf16(ph.v, bl, acc[tt], 0, 0, 0);
            acc[tt] = __builtin_amdgcn_mfma_f32_16x16x32_bf16(pl.v, bh, acc[tt], 0, 0, 0);
        }
    }

    // ---- cross-wave reduce of D (16 rows x 64 dims) ----
    #pragma unroll
    for (int tt = 0; tt < 4; ++tt) red[w][tt][lane] = acc[tt];
    __syncthreads();

    #pragma unroll
    for (int idx = t; idx < 16 * OUTD; idx += 512) {
        int row = idx >> 6, n = idx & 63;
        int ln = (row >> 2) * 16 + (n & 15);
        int reg = row & 3;
        float v = 0.f;
        #pragma unroll
        for (int ww = 0; ww < 8; ++ww)
            v += ((const float*)&red[ww][n >> 4][ln])[reg];
        hp[(rowbase + row) * OUTD + n] = v;
    }
}

extern "C" void kernel_launch(void* const* d_in, const int* in_sizes, int n_in,
                              void* d_out, int out_size, void* d_ws, size_t ws_size,
                              hipStream_t stream) {
    const float* x   = (const float*)d_in[0];
    const int*   adj = (const int*)d_in[1];
    const float* W   = (const float*)d_in[2];
    const float* a   = (const float*)d_in[3];

    float* out  = (float*)d_out;
    float* hp   = out;                                  // (B,N,OUT)
    float* attn = out + (size_t)BB * NN * OUTD;         // (B,N,N)

    char* ws = (char*)d_ws;
    short* hT_hi = (short*)ws;                           // 2 MB
    short* hT_lo = hT_hi + (size_t)BB * OUTD * NN;       // 2 MB
    float* si    = (float*)(hT_lo + (size_t)BB * OUTD * NN);
    float* sj    = si + (size_t)BB * NN;

    k1_hproj<<<BB * NN / 16, 256, 0, stream>>>(x, W, a, hT_hi, hT_lo, si, sj);
    k23<<<BB * NN / 16, 512, 0, stream>>>(adj, si, sj, hT_hi, hT_lo, attn, hp);
}